// Round 1
// 653.340 us; speedup vs baseline: 2.5810x; 2.5810x over previous
//
#include <hip/hip_runtime.h>

// Problem: out[j] = max(x[j], -c[rank_j]) per row, where rank_j = position of j
// in stable ascending sort of key = x*rho.  B=4096 rows, P=8192.
//
// Strategy: per-row MSD bucket (top 13 bits of monotone-u32 key, 8192 bins)
// + within-bin exact rank count on the residual 32 bits ((key<<13)|j, distinct).
//
// R1 change: phase 4 iterates by ELEMENT (keys already in registers) instead of
// by sorted POSITION. The old position-order loop contained a serial dependent-
// LDS-read walk over empty bins; the ~3000-bin empty gap around key==0 cost one
// straggler thread ~420K cycles/block (the measured 190us/block round).
// Element order needs no bin search at all: b = key>>19, lo = cnt[b-1], hi = cnt[b].
// Also: x stays in registers (no scattered re-gather) and the output store
// becomes two coalesced float4 stores (no scattered 4B write inflation).

constexpr int P_LEN  = 8192;   // row length == #bins (13 bits)
constexpr int BDIM   = 1024;   // threads per block
constexpr int EPT    = P_LEN / BDIM;  // 8 elements per thread

__device__ __forceinline__ unsigned fkey(float f) {
    unsigned u = __float_as_uint(f);
    // order-preserving map: negatives -> ~u (descending mag fixed), positives -> u|sign
    return (u & 0x80000000u) ? ~u : (u | 0x80000000u);
}

__global__ __launch_bounds__(BDIM)
void qp_rank_kernel(const float* __restrict__ x,
                    const float* __restrict__ rho,
                    const float* __restrict__ c,
                    float* __restrict__ out)
{
    __shared__ unsigned cnt[P_LEN];  // 32 KB: histogram -> exclusive bases -> bin ends
    __shared__ unsigned mem[P_LEN];  // 32 KB: scratch (scan) then bin-grouped members

    const int row  = blockIdx.x;
    const int t    = threadIdx.x;
    const int j0   = t * EPT;
    const int lane = t & 63;
    const int wid  = t >> 6;

    const float* __restrict__ xr   = x   + (size_t)row * P_LEN;
    const float* __restrict__ rr   = rho + (size_t)row * P_LEN;
    float*       __restrict__ outr = out + (size_t)row * P_LEN;

    // ---- phase 0: zero histogram (vectorized) ----
    uint4 z4 = make_uint4(0u, 0u, 0u, 0u);
    ((uint4*)cnt)[t * 2]     = z4;
    ((uint4*)cnt)[t * 2 + 1] = z4;
    __syncthreads();

    // ---- phase 1: load, compute keys, histogram ----
    float4 xa = ((const float4*)(xr + j0))[0];
    float4 xb = ((const float4*)(xr + j0))[1];
    float4 ra = ((const float4*)(rr + j0))[0];
    float4 rb = ((const float4*)(rr + j0))[1];
    float xs[EPT] = {xa.x, xa.y, xa.z, xa.w, xb.x, xb.y, xb.z, xb.w};
    float rs[EPT] = {ra.x, ra.y, ra.z, ra.w, rb.x, rb.y, rb.z, rb.w};
    unsigned key[EPT];
#pragma unroll
    for (int k = 0; k < EPT; ++k) {
        key[k] = fkey(xs[k] * rs[k]);
        atomicAdd(&cnt[key[k] >> 19], 1u);
    }
    __syncthreads();

    // ---- phase 2: exclusive scan of cnt (8192 bins) in place ----
    uint4 la = ((const uint4*)&cnt[j0])[0];
    uint4 lb = ((const uint4*)&cnt[j0])[1];
    unsigned l[EPT] = {la.x, la.y, la.z, la.w, lb.x, lb.y, lb.z, lb.w};
    unsigned s = 0;
#pragma unroll
    for (int k = 0; k < EPT; ++k) s += l[k];

    unsigned incl = s;
#pragma unroll
    for (int d = 1; d < 64; d <<= 1) {
        unsigned v = __shfl_up(incl, d, 64);
        if (lane >= d) incl += v;
    }
    if (lane == 63) mem[wid] = incl;            // wave totals (mem is free scratch here)
    __syncthreads();
    if (t == 0) {
        unsigned acc = 0;
        for (int w = 0; w < BDIM / 64; ++w) { unsigned v = mem[w]; mem[w] = acc; acc += v; }
    }
    __syncthreads();
    unsigned base = mem[wid] + (incl - s);      // exclusive prefix for this thread
    unsigned b0 = base, b1, b2, b3, b4, b5, b6, b7;
    b1 = b0 + l[0]; b2 = b1 + l[1]; b3 = b2 + l[2]; b4 = b3 + l[3];
    b5 = b4 + l[4]; b6 = b5 + l[5]; b7 = b6 + l[6];
    ((uint4*)&cnt[j0])[0] = make_uint4(b0, b1, b2, b3);
    ((uint4*)&cnt[j0])[1] = make_uint4(b4, b5, b6, b7);
    __syncthreads();   // also orders mem[wid] reads before scatter overwrites mem

    // ---- phase 3: scatter residuals into bin-grouped member list ----
#pragma unroll
    for (int k = 0; k < EPT; ++k) {
        unsigned b   = key[k] >> 19;
        unsigned pos = atomicAdd(&cnt[b], 1u);          // cnt[b] becomes end-of-bin
        mem[pos] = (key[k] << 13) | (unsigned)(j0 + k); // low19(key)<<13 | idx
    }
    __syncthreads();

    // ---- phase 4: element-order rank (no bin search/walk needed) ----
    // After phase 3: cnt[b] = end of bin b, so start of bin b = cnt[b-1] (0 for b==0).
    float res[EPT];
#pragma unroll 1
    for (int k = 0; k < EPT; ++k) {
        const unsigned kk   = key[k];
        const unsigned b    = kk >> 19;
        const unsigned lo   = (b == 0u) ? 0u : cnt[b - 1];
        const unsigned hi   = cnt[b];
        const unsigned mine = (kk << 13) | (unsigned)(j0 + k);
        unsigned r = lo;
        for (unsigned q = lo; q < hi; ++q)
            r += (mem[q] < mine) ? 1u : 0u;             // exact rank (values distinct)
        res[k] = fmaxf(xs[k], -c[r]);                   // c gather: 32 KB, L1/L2-hot
    }
    // coalesced output store (j = j0+k is contiguous)
    ((float4*)(outr + j0))[0] = make_float4(res[0], res[1], res[2], res[3]);
    ((float4*)(outr + j0))[1] = make_float4(res[4], res[5], res[6], res[7]);
}

extern "C" void kernel_launch(void* const* d_in, const int* in_sizes, int n_in,
                              void* d_out, int out_size, void* d_ws, size_t ws_size,
                              hipStream_t stream) {
    const float* x   = (const float*)d_in[0];
    const float* rho = (const float*)d_in[1];
    const float* c   = (const float*)d_in[2];
    float* out = (float*)d_out;
    const int rows = in_sizes[0] / P_LEN;   // 4096
    qp_rank_kernel<<<rows, BDIM, 0, stream>>>(x, rho, c, out);
}

// Round 2
// 433.142 us; speedup vs baseline: 3.8931x; 1.5084x over previous
//
#include <hip/hip_runtime.h>

// Problem: out[j] = max(x[j], -c[rank_j]) per row, where rank_j = position of j
// in stable ascending sort of key = x*rho.  B=4096 rows, P=8192.
//
// R2: two-level adaptive binning. The R1 profile showed the within-bin rank
// scan dominating (Sigma bin_size^2 ~ 650K LDS reads/row: float keys cluster
// ~all 8192 elements into ~300 of the 8192 top-13-bit bins). Level 2 uses the
// level-1 histogram to FLATTEN the distribution: element in bin b (start s_b,
// size sz_b) maps to bin2 = s_b + (sz_b * next13bits(key)) >> 13. This is
// monotone in the key (disjoint ordered ranges per b, monotone in r within b),
// occupies its own slice of position space, and yields ~Poisson(1) bin2 sizes
// -> Sigma size^2 ~ 16K reads/row. Same-bin2 elements share the top 13 key
// bits, so the exact residual comparison (key<<13)|idx still gives the stable
// rank. Level-1 scatter (hot-bin serialized atomics) is deleted entirely.

constexpr int P_LEN  = 8192;   // row length == #bins (13 bits)
constexpr int BDIM   = 1024;   // threads per block
constexpr int EPT    = P_LEN / BDIM;  // 8 elements per thread

__device__ __forceinline__ unsigned fkey(float f) {
    unsigned u = __float_as_uint(f);
    // order-preserving map: negatives -> ~u (descending mag fixed), positives -> u|sign
    return (u & 0x80000000u) ? ~u : (u | 0x80000000u);
}

// Exclusive scan of cnt[0..8191] in place: cnt[i] <- sum of cnt[0..i-1].
// wt = 16-entry scratch (we pass mem; only used before mem's scatter role).
__device__ __forceinline__ void scan_bins(unsigned* cnt, unsigned* wt,
                                          int t, int lane, int wid, int j0)
{
    uint4 la = ((const uint4*)&cnt[j0])[0];
    uint4 lb = ((const uint4*)&cnt[j0])[1];
    unsigned l[EPT] = {la.x, la.y, la.z, la.w, lb.x, lb.y, lb.z, lb.w};
    unsigned s = 0;
#pragma unroll
    for (int k = 0; k < EPT; ++k) s += l[k];

    unsigned incl = s;
#pragma unroll
    for (int d = 1; d < 64; d <<= 1) {
        unsigned v = __shfl_up(incl, d, 64);
        if (lane >= d) incl += v;
    }
    if (lane == 63) wt[wid] = incl;            // wave totals
    __syncthreads();
    if (t == 0) {
        unsigned acc = 0;
        for (int w = 0; w < BDIM / 64; ++w) { unsigned v = wt[w]; wt[w] = acc; acc += v; }
    }
    __syncthreads();
    unsigned base = wt[wid] + (incl - s);      // exclusive prefix for this thread
    unsigned b0 = base;
    unsigned b1 = b0 + l[0], b2 = b1 + l[1], b3 = b2 + l[2], b4 = b3 + l[3];
    unsigned b5 = b4 + l[4], b6 = b5 + l[5], b7 = b6 + l[6];
    ((uint4*)&cnt[j0])[0] = make_uint4(b0, b1, b2, b3);
    ((uint4*)&cnt[j0])[1] = make_uint4(b4, b5, b6, b7);
    __syncthreads();   // bases visible to all; also orders wt reads vs later mem writes
}

__global__ __launch_bounds__(BDIM)
void qp_rank_kernel(const float* __restrict__ x,
                    const float* __restrict__ rho,
                    const float* __restrict__ c,
                    float* __restrict__ out)
{
    __shared__ unsigned cnt[P_LEN];  // 32 KB: hist1 -> starts1 -> hist2 -> starts2 -> bin2 ends
    __shared__ unsigned mem[P_LEN];  // 32 KB: scan scratch, then bin2-grouped members

    const int row  = blockIdx.x;
    const int t    = threadIdx.x;
    const int j0   = t * EPT;
    const int lane = t & 63;
    const int wid  = t >> 6;

    const float* __restrict__ xr   = x   + (size_t)row * P_LEN;
    const float* __restrict__ rr   = rho + (size_t)row * P_LEN;
    float*       __restrict__ outr = out + (size_t)row * P_LEN;

    // ---- phase 0: zero histogram (vectorized) ----
    uint4 z4 = make_uint4(0u, 0u, 0u, 0u);
    ((uint4*)cnt)[t * 2]     = z4;
    ((uint4*)cnt)[t * 2 + 1] = z4;
    __syncthreads();

    // ---- phase 1: load, compute keys, level-1 histogram (top 13 bits) ----
    float4 xa = ((const float4*)(xr + j0))[0];
    float4 xb = ((const float4*)(xr + j0))[1];
    float4 ra = ((const float4*)(rr + j0))[0];
    float4 rb = ((const float4*)(rr + j0))[1];
    float xs[EPT] = {xa.x, xa.y, xa.z, xa.w, xb.x, xb.y, xb.z, xb.w};
    float rs[EPT] = {ra.x, ra.y, ra.z, ra.w, rb.x, rb.y, rb.z, rb.w};
    unsigned key[EPT];
#pragma unroll
    for (int k = 0; k < EPT; ++k) {
        key[k] = fkey(xs[k] * rs[k]);
        atomicAdd(&cnt[key[k] >> 19], 1u);
    }
    __syncthreads();

    // ---- phase 2: scan1 -> cnt[b] = start of level-1 bin b ----
    scan_bins(cnt, mem, t, lane, wid, j0);

    // ---- phase 3: adaptive refinement: bin2 = start_b + (size_b * r) >> 13 ----
    // r = next 13 key bits (bits 18:6). Monotone within b; range [s_b, e_b) disjoint
    // and ordered across b => bin2 is a monotone re-binning with ~uniform occupancy.
    unsigned bin2[EPT];
#pragma unroll
    for (int k = 0; k < EPT; ++k) {
        const unsigned b   = key[k] >> 19;
        const unsigned s_b = cnt[b];
        const unsigned e_b = (b == (unsigned)(P_LEN - 1)) ? (unsigned)P_LEN : cnt[b + 1];
        const unsigned sz  = e_b - s_b;                    // >= 1 (b is occupied)
        const unsigned r   = (key[k] >> 6) & 0x1FFFu;
        bin2[k] = s_b + ((sz * r) >> 13);                  // sz<=2^13, r<2^13: fits 32b
    }
    __syncthreads();   // all starts1 reads done before re-zero

    // ---- phase 4: re-zero, level-2 histogram (near-conflict-free atomics) ----
    ((uint4*)cnt)[t * 2]     = z4;
    ((uint4*)cnt)[t * 2 + 1] = z4;
    __syncthreads();
#pragma unroll
    for (int k = 0; k < EPT; ++k) atomicAdd(&cnt[bin2[k]], 1u);
    __syncthreads();

    // ---- phase 5: scan2 -> cnt[b2] = start of level-2 bin b2 ----
    scan_bins(cnt, mem, t, lane, wid, j0);

    // ---- phase 6: scatter residuals into bin2-grouped member list ----
    // Same-bin2 elements share the top 13 key bits, so (key<<13)|idx ordering
    // == full (key, idx) ordering within a bin2.
#pragma unroll
    for (int k = 0; k < EPT; ++k) {
        unsigned pos = atomicAdd(&cnt[bin2[k]], 1u);       // cnt[b2] becomes end-of-bin2
        mem[pos] = (key[k] << 13) | (unsigned)(j0 + k);
    }
    __syncthreads();

    // ---- phase 7: exact rank over tiny bin2s, fused epilogue ----
    float res[EPT];
#pragma unroll 1
    for (int k = 0; k < EPT; ++k) {
        const unsigned b2   = bin2[k];
        const unsigned lo   = (b2 == 0u) ? 0u : cnt[b2 - 1];
        const unsigned hi   = cnt[b2];
        const unsigned mine = (key[k] << 13) | (unsigned)(j0 + k);
        unsigned r = lo;
        for (unsigned q = lo; q < hi; ++q)
            r += (mem[q] < mine) ? 1u : 0u;                // exact stable rank
        res[k] = fmaxf(xs[k], -c[r]);                      // c gather: 32 KB, L2-hot
    }
    // coalesced output store (j = j0+k is contiguous)
    ((float4*)(outr + j0))[0] = make_float4(res[0], res[1], res[2], res[3]);
    ((float4*)(outr + j0))[1] = make_float4(res[4], res[5], res[6], res[7]);
}

extern "C" void kernel_launch(void* const* d_in, const int* in_sizes, int n_in,
                              void* d_out, int out_size, void* d_ws, size_t ws_size,
                              hipStream_t stream) {
    const float* x   = (const float*)d_in[0];
    const float* rho = (const float*)d_in[1];
    const float* c   = (const float*)d_in[2];
    float* out = (float*)d_out;
    const int rows = in_sizes[0] / P_LEN;   // 4096
    qp_rank_kernel<<<rows, BDIM, 0, stream>>>(x, rho, c, out);
}

// Round 3
// 338.540 us; speedup vs baseline: 4.9810x; 1.2794x over previous
//
#include <hip/hip_runtime.h>

// Problem: out[j] = max(x[j], -c[rank_j]) per row, rank_j = position of j in
// stable ascending sort of key = x*rho.  B=4096 rows, P=8192.
//
// R3: latency attack. R2 was 1-block-resident (49.6% occ) and latency-bound.
//  - LDS 64KB -> 48KB: counters packed as ushort halves (all counts <= 8192).
//    Packing: bin v -> word (v & 4095), half (v >> 12). Adjacent hot bins hit
//    different words; atomic add of 1 or 1<<16 cannot carry across halves.
//  - Packed SIMD-within-register scan: one shuffle chain scans both half-
//    sequences at once; uint4-vectorized read AND write, half the traffic.
//  - __launch_bounds__(1024, 8): VGPR <= 64 so 2 blocks x 16 waves fit.
//  - Wave-parallel wave-total scan (was a serial t==0 dependent-LDS loop x2).
//  - Rank phase split: compute 8 ranks, then batch-issue 8 c[] gathers.

constexpr int P_LEN  = 8192;            // row length == #bins (13 bits)
constexpr int BDIM   = 1024;            // threads per block
constexpr int EPT    = P_LEN / BDIM;    // 8 elements per thread
constexpr int NW     = BDIM / 64;       // 16 waves
constexpr int CWORDS = P_LEN / 2;       // 4096 packed counter words

__device__ __forceinline__ unsigned fkey(float f) {
    unsigned u = __float_as_uint(f);
    // order-preserving map: negatives -> ~u, positives -> u|sign
    return (u & 0x80000000u) ? ~u : (u | 0x80000000u);
}

// packed-counter helpers: bin v in [0,8192) lives in half (v>>12) of word (v&4095)
__device__ __forceinline__ unsigned pk_word(unsigned v) { return v & (CWORDS - 1u); }
__device__ __forceinline__ unsigned pk_inc(unsigned v)  { return (v & (unsigned)CWORDS) ? 0x10000u : 1u; }
__device__ __forceinline__ unsigned pk_get(unsigned w, unsigned v) { return (w >> ((v >> 12) << 4)) & 0xFFFFu; }
// ushort index of bin v's half (little-endian: lo half = 2*word, hi = 2*word+1)
__device__ __forceinline__ unsigned pk_us(unsigned v)   { return ((v & (CWORDS - 1u)) << 1) | (v >> 12); }

// In-place exclusive scan of 8192 packed counts (bin order: all lo halves 0..4095,
// then all hi halves). After: word w = (startLo(w)) | (startHi(w) << 16).
// wt: NW+1 scratch words. Fully wave-parallel (no serial thread-0 loop).
__device__ __forceinline__ void scan_packed(unsigned* cnt, unsigned* wt,
                                            int t, int lane, int wid)
{
    uint4 cw = ((const uint4*)cnt)[t];               // words 4t..4t+3
    const unsigned p1 = cw.x, p2 = cw.x + cw.y, p3 = cw.x + cw.y + cw.z;
    const unsigned s  = p3 + cw.w;                   // packed per-thread sums
    unsigned incl = s;
#pragma unroll
    for (int d = 1; d < 64; d <<= 1) {
        unsigned v = __shfl_up(incl, d, 64);
        if (lane >= d) incl += v;
    }
    if (lane == 63) wt[wid] = incl;                  // packed wave totals
    __syncthreads();
    if (t < 64) {                                    // wave 0 scans the 16 totals
        unsigned v = (lane < NW) ? wt[lane] : 0u;
        const unsigned orig = v;
#pragma unroll
        for (int d = 1; d < NW; d <<= 1) {
            unsigned u = __shfl_up(v, d, 64);
            if (lane >= d) v += u;
        }
        if (lane < NW)     wt[lane] = v - orig;      // exclusive wave prefix
        if (lane == NW - 1) wt[NW]  = v;             // packed grand totals
    }
    __syncthreads();
    const unsigned base = wt[wid] + (incl - s);      // packed exclusive prefix
    const unsigned totL = wt[NW] & 0xFFFFu;          // #elements in lo-half bins
    const unsigned q0 = base, q1 = base + p1, q2 = base + p2, q3 = base + p3;
    uint4 out;
    out.x = (q0 & 0xFFFFu) | ((totL + (q0 >> 16)) << 16);
    out.y = (q1 & 0xFFFFu) | ((totL + (q1 >> 16)) << 16);
    out.z = (q2 & 0xFFFFu) | ((totL + (q2 >> 16)) << 16);
    out.w = (q3 & 0xFFFFu) | ((totL + (q3 >> 16)) << 16);
    ((uint4*)cnt)[t] = out;
    __syncthreads();
}

__global__ __launch_bounds__(BDIM, 8)   // 8 waves/SIMD -> 2 blocks/CU; VGPR <= 64
void qp_rank_kernel(const float* __restrict__ x,
                    const float* __restrict__ rho,
                    const float* __restrict__ c,
                    float* __restrict__ out)
{
    __shared__ unsigned cnt[CWORDS];   // 16 KB packed counters/starts/ends
    __shared__ unsigned mem[P_LEN];    // 32 KB bin2-grouped members
    __shared__ unsigned wt[NW + 1];    // scan scratch

    const int row  = blockIdx.x;
    const int t    = threadIdx.x;
    const int j0   = t * EPT;
    const int lane = t & 63;
    const int wid  = t >> 6;

    const float* __restrict__ xr   = x   + (size_t)row * P_LEN;
    const float* __restrict__ rr   = rho + (size_t)row * P_LEN;
    float*       __restrict__ outr = out + (size_t)row * P_LEN;
    const unsigned short* usview = (const unsigned short*)cnt;

    // ---- phase 0: zero packed histogram (1 uint4 per thread) ----
    const uint4 z4 = make_uint4(0u, 0u, 0u, 0u);
    ((uint4*)cnt)[t] = z4;
    __syncthreads();

    // ---- phase 1: load, keys, level-1 histogram (top 13 bits) ----
    float4 xa = ((const float4*)(xr + j0))[0];
    float4 xb = ((const float4*)(xr + j0))[1];
    float4 ra = ((const float4*)(rr + j0))[0];
    float4 rb = ((const float4*)(rr + j0))[1];
    float xs[EPT] = {xa.x, xa.y, xa.z, xa.w, xb.x, xb.y, xb.z, xb.w};
    float rs[EPT] = {ra.x, ra.y, ra.z, ra.w, rb.x, rb.y, rb.z, rb.w};
    unsigned key[EPT];
#pragma unroll
    for (int k = 0; k < EPT; ++k) {
        key[k] = fkey(xs[k] * rs[k]);
        const unsigned b = key[k] >> 19;
        atomicAdd(&cnt[pk_word(b)], pk_inc(b));
    }
    __syncthreads();

    // ---- phase 2: scan1 -> packed starts of level-1 bins ----
    scan_packed(cnt, wt, t, lane, wid);

    // ---- phase 3: adaptive refinement: bin2 = s_b + (sz_b * r) >> 13 ----
    // r = next 13 key bits. Monotone re-binning onto position space [0,8192),
    // disjoint ordered ranges per b -> same bin2 implies same top-13 key bits.
    unsigned bin2[EPT];
#pragma unroll
    for (int k = 0; k < EPT; ++k) {
        const unsigned b   = key[k] >> 19;
        const unsigned s_b = usview[pk_us(b)];
        const unsigned e_b = (b == (unsigned)(P_LEN - 1)) ? (unsigned)P_LEN
                                                          : usview[pk_us(b + 1)];
        const unsigned sz  = e_b - s_b;
        const unsigned r   = (key[k] >> 6) & 0x1FFFu;
        bin2[k] = s_b + ((sz * r) >> 13);
    }
    __syncthreads();   // all starts1 reads complete before re-zero

    // ---- phase 4: re-zero, level-2 histogram (near-conflict-free) ----
    ((uint4*)cnt)[t] = z4;
    __syncthreads();
#pragma unroll
    for (int k = 0; k < EPT; ++k)
        atomicAdd(&cnt[pk_word(bin2[k])], pk_inc(bin2[k]));
    __syncthreads();

    // ---- phase 5: scan2 -> packed starts of level-2 bins ----
    scan_packed(cnt, wt, t, lane, wid);

    // ---- phase 6: scatter residuals; cnt halves become bin2 ends ----
    unsigned mine[EPT];
#pragma unroll
    for (int k = 0; k < EPT; ++k) {
        mine[k] = (key[k] << 13) | (unsigned)(j0 + k);
        const unsigned b2 = bin2[k];
        const unsigned old = atomicAdd(&cnt[pk_word(b2)], pk_inc(b2));
        mem[pk_get(old, b2)] = mine[k];
    }
    __syncthreads();

    // ---- phase 7: exact rank over tiny bin2s (fully unrolled: regs only) ----
    unsigned rnk[EPT];
#pragma unroll
    for (int k = 0; k < EPT; ++k) {
        const unsigned b2 = bin2[k];
        const unsigned lo = (b2 == 0u) ? 0u : usview[pk_us(b2 - 1)];
        const unsigned hi = usview[pk_us(b2)];
        unsigned r = lo;
#pragma unroll 1
        for (unsigned q = lo; q < hi; ++q)
            r += (mem[q] < mine[k]) ? 1u : 0u;       // exact stable rank
        rnk[k] = r;
    }
    // ---- phase 8: batched c gathers (8 loads in flight), fused epilogue ----
    float res[EPT];
#pragma unroll
    for (int k = 0; k < EPT; ++k) res[k] = fmaxf(xs[k], -c[rnk[k]]);
    ((float4*)(outr + j0))[0] = make_float4(res[0], res[1], res[2], res[3]);
    ((float4*)(outr + j0))[1] = make_float4(res[4], res[5], res[6], res[7]);
}

extern "C" void kernel_launch(void* const* d_in, const int* in_sizes, int n_in,
                              void* d_out, int out_size, void* d_ws, size_t ws_size,
                              hipStream_t stream) {
    const float* x   = (const float*)d_in[0];
    const float* rho = (const float*)d_in[1];
    const float* c   = (const float*)d_in[2];
    float* out = (float*)d_out;
    const int rows = in_sizes[0] / P_LEN;   // 4096
    qp_rank_kernel<<<rows, BDIM, 0, stream>>>(x, rho, c, out);
}